// Round 2
// baseline (185.817 us; speedup 1.0000x reference)
//
#include <hip/hip_runtime.h>
#include <cmath>

// Problem constants
#define Bsz 32
#define Lsz 256
#define Asz 20

// k1 geometry: wg = (i, half). Each wg streams 128 p-blocks (204.8 KB)
// through 8 double-buffered stages of 16 p-blocks (25.6 KB) staged with
// global_load_lds (direct HBM->LDS, no VGPR round-trip).
#define NHALF 2
#define HALF 128               // p per workgroup
#define SUBB 16                // p-blocks per stage
#define NST (HALF / SUBB)      // 8 stages
#define STF (SUBB * 400)       // 6400 floats per stage buffer
#define BLK1 640               // t = j*32 + b (j = t>>5 in 0..19, b = t&31)
#define NWG1 (Lsz * NHALF)     // 512 workgroups -> exactly 2 per CU, all resident

// Workspace offsets (floats). Total ~364K floats = 1.45 MB.
#define OFF_G 0                                   // [h][i][b][j]  p>i gather partials
#define OFF_C (NHALF * Lsz * Bsz * Asz)           // [h][i][j]     b-independent (p<=i)
#define OFF_E (OFF_C + NHALF * Lsz * Asz)         // [h][i][b]     energy pair partials
#define OFF_RSQ (OFF_E + NHALF * Lsz * Bsz)       // [512] per-wg sum w^2
#define OFF_RAB (OFF_RSQ + NWG1)                  // [512] per-wg sum |w|
#define OFF_K2  (OFF_RAB + NWG1)                  // [L*B] per-(i,b) lse-energy

// Direct global->LDS 16B copy. LDS dest must be wave-uniform base; HW writes
// lane l at base + l*16. Global source is per-lane.
__device__ __forceinline__ void cp16(const float* g, float* l) {
  __builtin_amdgcn_global_load_lds(
      (const __attribute__((address_space(1))) void*)g,
      (__attribute__((address_space(3))) void*)l, 16, 0, 0);
}

// Kernel 1: stream all of w_pair once. Raw (unpadded) LDS stage layout; the
// lane map t=j*32+b keeps the gather <=2-way bank-aliased (free). Stats are
// computed from LDS readback (b128, conflict-free).
__global__ __launch_bounds__(BLK1, 5) void k1(const int* __restrict__ x,
                                              const float* __restrict__ wp,
                                              float* __restrict__ ws) {
  const int wg = blockIdx.x;
  const int i = wg >> 1;
  const int h = wg & 1;
  const int pbase = h * HALF;
  const int t = threadIdx.x;
  const int j = t >> 5;          // 0..19
  const int b = t & 31;          // 0..31

  __shared__ float buf[2][STF];        // 2 x 25.6 KB
  __shared__ int   xs[HALF * Bsz];     // [dp][b] -> bank = b, conflict-free (16 KB)
  __shared__ int   xi[Bsz];
  __shared__ float wred[32];

  const float* wrow = wp + (size_t)(i * Lsz + pbase) * 400;
  const int wbase = (t >> 6) << 8;     // wave-uniform float offset (wave w -> w*256)

  // Issue stage 0 (3 call sites cover 6400 floats: 640*4 + 640*4 + 320*4)
  {
    const float* g = wrow;
    cp16(g + t * 4, &buf[0][wbase]);
    cp16(g + 2560 + t * 4, &buf[0][2560 + wbase]);
    if (t < 320) cp16(g + 5120 + t * 4, &buf[0][5120 + wbase]);
  }
  // Stage x for this half (L2-resident, once per wg)
  for (int k = t; k < HALF * Bsz; k += BLK1) {
    int dp = k >> 5, bb = k & 31;
    xs[k] = x[bb * Lsz + pbase + dp];
  }
  if (t < Bsz) xi[t] = x[t * Lsz + i];
  __syncthreads();   // vmcnt(0)+lgkmcnt(0) drain: buf0 + xs ready

  float accJ = 0.f, accE = 0.f, accC = 0.f, rsq = 0.f, rab = 0.f;
  const int jbase = j * Asz;

  for (int s = 0; s < NST; ++s) {
    const float* blk = buf[s & 1];

    // Issue next stage into the other buffer BEFORE processing: its HBM
    // latency hides under this stage's gathers + the co-resident wg's work.
    if (s + 1 < NST) {
      const float* g = wrow + (size_t)(s + 1) * STF;
      float* l = buf[(s + 1) & 1];
      cp16(g + t * 4, l + wbase);
      cp16(g + 2560 + t * 4, l + 2560 + wbase);
      if (t < 320) cp16(g + 5120 + t * 4, l + 5120 + wbase);
    }

    const int sp = s * SUBB;        // local p of stage start
    const int pg = pbase + sp;      // global p of stage start

    // --- accJ: p > i, all waves ---
    int ppstart = i + 1 - pg;
    if (ppstart < 0) ppstart = 0;
    for (int pp = ppstart; pp < SUBB; ++pp) {
      int xv = xs[((sp + pp) << 5) | b];
      accJ += blk[pp * 400 + jbase + xv];
    }
    // --- accE (lanes 0..31 of wave 0): all p ---
    if (t < Bsz) {
      const int ebase = xi[t] * Asz;
      #pragma unroll
      for (int pp = 0; pp < SUBB; ++pp) {
        int xv = xs[((sp + pp) << 5) | t];
        accE += blk[pp * 400 + ebase + xv];
      }
    } else if (t < Bsz + Asz) {
      // --- accC (lanes 32..51 of wave 0): p<i -> col 19; p==i -> diag ---
      const int jj = t - Bsz;
      int pend = i - pg;
      if (pend > SUBB) pend = SUBB;
      for (int pp = 0; pp < pend; ++pp) accC += blk[pp * 400 + jj * Asz + 19];
      const int pd = i - pg;
      if (pd >= 0 && pd < SUBB) accC += blk[pd * 400 + jj * Asz + jj];
    }

    // --- stats from LDS readback (contiguous b128, conflict-free) ---
    const float4* bf4 = (const float4*)blk;
    float4 v0 = bf4[t];
    float4 v1 = bf4[t + 640];
    rsq += v0.x*v0.x + v0.y*v0.y + v0.z*v0.z + v0.w*v0.w
         + v1.x*v1.x + v1.y*v1.y + v1.z*v1.z + v1.w*v1.w;
    rab += fabsf(v0.x)+fabsf(v0.y)+fabsf(v0.z)+fabsf(v0.w)
         + fabsf(v1.x)+fabsf(v1.y)+fabsf(v1.z)+fabsf(v1.w);
    if (t < 320) {
      float4 v2 = bf4[t + 1280];
      rsq += v2.x*v2.x + v2.y*v2.y + v2.z*v2.z + v2.w*v2.w;
      rab += fabsf(v2.x)+fabsf(v2.y)+fabsf(v2.z)+fabsf(v2.w);
    }
    __syncthreads();  // drain: next buffer fully written; all reads of blk done
  }

  ws[OFF_G + ((size_t)((h * Lsz + i) * Bsz + b)) * Asz + j] = accJ;
  if (t < Bsz) ws[OFF_E + (h * Lsz + i) * Bsz + t] = accE;
  else if (t < Bsz + Asz) ws[OFF_C + (h * Lsz + i) * Asz + (t - Bsz)] = accC;

  // reg-stat reduction: wave shuffle then tiny LDS pass
  for (int sft = 32; sft >= 1; sft >>= 1) {
    rsq += __shfl_down(rsq, sft);
    rab += __shfl_down(rab, sft);
  }
  if ((t & 63) == 0) { wred[t >> 6] = rsq; wred[16 + (t >> 6)] = rab; }
  __syncthreads();
  if (t == 0) {
    float a = 0.f, bb2 = 0.f;
    for (int w = 0; w < BLK1 / 64; ++w) { a += wred[w]; bb2 += wred[16 + w]; }
    ws[OFF_RSQ + wg] = a;
    ws[OFF_RAB + wg] = bb2;
  }
}

// Kernel 2: one block per i: assemble logits from the 2 half-partials,
// logsumexp per b, subtract energy, write per-(i,b) partial.
__global__ __launch_bounds__(BLK1) void k2(const int* __restrict__ x,
                                           const float* __restrict__ wsng,
                                           const float* __restrict__ ws,
                                           float* __restrict__ wso) {
  const int i = blockIdx.x;
  const int t = threadIdx.x;
  const int j = t >> 5, b = t & 31;
  __shared__ float l[Bsz * 21];

  float v = wsng[i * Asz + j];
  #pragma unroll
  for (int hh = 0; hh < NHALF; ++hh) {
    v += ws[OFF_C + (hh * Lsz + i) * Asz + j];
    v += ws[OFF_G + ((size_t)((hh * Lsz + i) * Bsz + b)) * Asz + j];
  }
  l[b * 21 + j] = v;
  __syncthreads();

  if (t < Bsz) {
    float m = -1e30f;
    #pragma unroll
    for (int jj = 0; jj < Asz; ++jj) m = fmaxf(m, l[t * 21 + jj]);
    float se = 0.f;
    #pragma unroll
    for (int jj = 0; jj < Asz; ++jj) se += __expf(l[t * 21 + jj] - m);
    float lse = m + __logf(se);
    float en = wsng[i * Asz + x[t * Lsz + i]];
    #pragma unroll
    for (int hh = 0; hh < NHALF; ++hh) en += ws[OFF_E + (hh * Lsz + i) * Bsz + t];
    wso[OFF_K2 + i * Bsz + t] = lse - en;
  }
}

// Kernel 3: final scalar.
__global__ __launch_bounds__(256) void k3(const float* __restrict__ wsng,
                                          const float* __restrict__ ws,
                                          float* __restrict__ out) {
  const int t = threadIdx.x;
  float ssq = 0.f, sab = 0.f;
  for (int k = t; k < Lsz * Asz; k += 256) {
    float v = wsng[k];
    ssq += v * v; sab += fabsf(v);
  }
  float psq = 0.f, pab = 0.f;
  for (int k = t; k < NWG1; k += 256) {
    psq += ws[OFF_RSQ + k];
    pab += ws[OFF_RAB + k];
  }
  float fe = 0.f;
  for (int k = t; k < Lsz * Bsz; k += 256) fe += ws[OFF_K2 + k];

  const float LP = 51.0f;  // 0.2 * (L-1)
  float val = fe * (1.0f / Bsz) + (ssq + sab) + LP * (psq + pab);

  __shared__ float red[256];
  red[t] = val;
  __syncthreads();
  for (int s = 128; s >= 1; s >>= 1) {
    if (t < s) red[t] += red[t + s];
    __syncthreads();
  }
  if (t == 0) out[0] = red[0];
}

extern "C" void kernel_launch(void* const* d_in, const int* in_sizes, int n_in,
                              void* d_out, int out_size, void* d_ws, size_t ws_size,
                              hipStream_t stream) {
  const int*   x       = (const int*)d_in[0];
  const float* wsingle = (const float*)d_in[1];
  const float* wpair   = (const float*)d_in[2];
  float* ws  = (float*)d_ws;
  float* out = (float*)d_out;

  k1<<<NWG1, BLK1, 0, stream>>>(x, wpair, ws);
  k2<<<Lsz, BLK1, 0, stream>>>(x, wsingle, ws, ws);
  k3<<<1, 256, 0, stream>>>(wsingle, ws, out);
}

// Round 3
// 184.059 us; speedup vs baseline: 1.0096x; 1.0096x over previous
//
#include <hip/hip_runtime.h>
#include <cmath>

// Problem constants
#define Bsz 32
#define Lsz 256
#define Asz 20

// k1 geometry: wg = (i, quarter). Each wg streams 64 p-blocks (102.4 KB)
// through 8 double-buffered stages of 8 p-blocks (12.8 KB) staged with
// global_load_lds. 320 threads (5 waves): t = jlo*32 + b, jlo in [0,10),
// each thread owns j = jlo and j = jlo+10. 4 wgs/CU resident (36 KB LDS,
// 20 waves) -> ~51 KB HBM in flight per CU, well above the ~9 KB needed
// to saturate the per-CU HBM share.
#define NQ 4
#define QP 64                  // p per workgroup
#define SUBB 8                 // p-blocks per stage
#define NST (QP / SUBB)        // 8 stages
#define STF (SUBB * 400)       // 3200 floats per stage buffer
#define BLK1 320
#define NWG1 (Lsz * NQ)        // 1024 workgroups -> exactly 4 per CU

// Workspace offsets (floats). Total ~719K floats = 2.9 MB.
// OFF_G layout transposed to [q][i][j][b] so k1 stores and k2 loads coalesce.
#define OFF_G 0
#define SZ_G (NQ * Lsz * Asz * Bsz)
#define OFF_C (OFF_G + SZ_G)                 // [q][i][j]  b-independent (p<=i)
#define SZ_C (NQ * Lsz * Asz)
#define OFF_E (OFF_C + SZ_C)                 // [q][i][b]  energy pair partials
#define SZ_E (NQ * Lsz * Bsz)
#define OFF_RSQ (OFF_E + SZ_E)               // [1024] per-wg sum w^2
#define OFF_RAB (OFF_RSQ + NWG1)             // [1024] per-wg sum |w|
#define OFF_K2  (OFF_RAB + NWG1)             // [L*B]  per-(i,b) lse-energy

// Direct global->LDS 16B copy. LDS dest is wave-uniform base + lane*16.
__device__ __forceinline__ void cp16(const float* g, float* l) {
  __builtin_amdgcn_global_load_lds(
      (const __attribute__((address_space(1))) void*)g,
      (__attribute__((address_space(3))) void*)l, 16, 0, 0);
}

// Stage one 800-float4 (12.8 KB) block with whole-wave-uniform cp16 rounds:
// r0: f4[0,320) by all threads; r1: f4[320,640); r2: waves 0-1 -> f4[640,768);
// r3: wave 2 -> f4[736,800) (overlap [736,768) rewrites identical data: benign).
__device__ __forceinline__ void stage_block(const float* g, float* l, int t) {
  const int wbase = (t >> 6) << 8;            // wave-uniform float offset
  cp16(g + 4 * t, l + wbase);
  cp16(g + 1280 + 4 * t, l + 1280 + wbase);
  if (t < 128) cp16(g + 2560 + 4 * t, l + 2560 + wbase);
  if (t >= 128 && t < 192) cp16(g + 2944 + 4 * (t - 128), l + 2944 + ((t - 128) & ~63) * 4 + ((t >> 6) == 2 ? 0 : 0));
}

// Kernel 1: stream all of w_pair once. Balanced per-thread work: every thread
// does accJ (<=8 reads/stage for 2 j's => <=16), threads jlo<8 add 1 accE read
// and (b<20) 1 conditional accC read. Stats from LDS readback (b128).
__global__ __launch_bounds__(BLK1, 5) void k1(const int* __restrict__ x,
                                              const float* __restrict__ wp,
                                              float* __restrict__ ws) {
  const int wg = blockIdx.x;
  const int i = wg >> 2;
  const int q = wg & 3;
  const int pbase = q * QP;
  const int t = threadIdx.x;
  const int jlo = t >> 5;        // 0..9
  const int b = t & 31;          // 0..31

  __shared__ float buf[2][STF];       // 2 x 12.8 KB
  __shared__ int   xs[QP * Bsz];      // [dp][b] -> bank = b (8 KB)
  __shared__ int   xi[Bsz];
  __shared__ float eRed[8][Bsz];      // accE partials over pp-slot
  __shared__ float cRed[8][Asz];      // accC partials over pp-slot
  __shared__ float wred[16];

  const float* wrow = wp + (size_t)(i * Lsz + pbase) * 400;
  const int wbase = (t >> 6) << 8;    // wave-uniform float offset (wave w -> w*256)

  // ---- prologue: issue stage 0 (wave-uniform rounds), stage x ----
  {
    const float* g = wrow;
    float* l = &buf[0][0];
    cp16(g + 4 * t, l + wbase);                       // f4 [0,320)
    cp16(g + 1280 + 4 * t, l + 1280 + wbase);         // f4 [320,640)
    if (t < 128) cp16(g + 2560 + 4 * t, l + 2560 + wbase);          // f4 [640,768)
    if (t >= 128 && t < 192) cp16(g + 2944 + 4 * (t - 128), l + 2944); // f4 [736,800), wave 2, dup-write overlap benign
  }
  for (int k = t; k < QP * Bsz; k += BLK1) {
    int dp = k >> 5, bb = k & 31;
    xs[k] = x[bb * Lsz + pbase + dp];
  }
  if (t < Bsz) xi[t] = x[t * Lsz + i];
  __syncthreads();   // drains vmcnt+lgkmcnt: buf0 + xs + xi ready

  const int xib = xi[b];
  float accJ0 = 0.f, accJ1 = 0.f, accE = 0.f, accC = 0.f, rsq = 0.f, rab = 0.f;
  const int jb0 = jlo * Asz;
  const int jb1 = (jlo + 10) * Asz;

  for (int s = 0; s < NST; ++s) {
    const float* blk = buf[s & 1];

    // issue next stage into the other buffer (HBM latency hides under the
    // gathers + the 3 co-resident wgs)
    if (s + 1 < NST) {
      const float* g = wrow + (size_t)(s + 1) * STF;
      float* l = &buf[(s + 1) & 1][0];
      cp16(g + 4 * t, l + wbase);
      cp16(g + 1280 + 4 * t, l + 1280 + wbase);
      if (t < 128) cp16(g + 2560 + 4 * t, l + 2560 + wbase);
      if (t >= 128 && t < 192) cp16(g + 2944 + 4 * (t - 128), l + 2944);
    }

    const int sp = s * SUBB;        // local p of stage start
    const int pg = pbase + sp;      // global p of stage start

    // --- accJ: p > i, two j's per thread (block-uniform trip count) ---
    int ppstart = i + 1 - pg;
    if (ppstart < 0) ppstart = 0;
    for (int pp = ppstart; pp < SUBB; ++pp) {
      int xv = xs[((sp + pp) << 5) | b];
      const float* r = blk + pp * 400 + xv;
      accJ0 += r[jb0];
      accJ1 += r[jb1];
    }

    // --- accE (threads jlo<8: pp=jlo, own b; all p count) ---
    if (jlo < 8) {
      int xv = xs[((sp + jlo) << 5) | b];
      accE += blk[jlo * 400 + xib * Asz + xv];
      // --- accC (additionally b<20: jrow=b): p<i -> col 19; p==i -> diag ---
      if (b < Asz) {
        int p = pg + jlo;
        if (p < i) accC += blk[jlo * 400 + b * Asz + 19];
        else if (p == i) accC += blk[jlo * 400 + b * Asz + b];
      }
    }

    // --- stats from LDS readback (b128, conflict-free, each elem once) ---
    const float4* bf4 = (const float4*)blk;
    float4 v0 = bf4[t];
    float4 v1 = bf4[t + 320];
    rsq += v0.x*v0.x + v0.y*v0.y + v0.z*v0.z + v0.w*v0.w
         + v1.x*v1.x + v1.y*v1.y + v1.z*v1.z + v1.w*v1.w;
    rab += fabsf(v0.x)+fabsf(v0.y)+fabsf(v0.z)+fabsf(v0.w)
         + fabsf(v1.x)+fabsf(v1.y)+fabsf(v1.z)+fabsf(v1.w);
    if (t < 160) {
      float4 v2 = bf4[t + 640];
      rsq += v2.x*v2.x + v2.y*v2.y + v2.z*v2.z + v2.w*v2.w;
      rab += fabsf(v2.x)+fabsf(v2.y)+fabsf(v2.z)+fabsf(v2.w);
    }
    __syncthreads();  // next buffer fully landed; all reads of blk done
  }

  // ---- epilogue ----
  // accJ: OFF_G[q][i][j][b] -> ws[base+t], ws[base+t+320]: fully coalesced
  {
    const size_t gb = OFF_G + (size_t)(q * Lsz + i) * Asz * Bsz;
    ws[gb + t] = accJ0;
    ws[gb + t + 320] = accJ1;
  }
  if (jlo < 8) {
    eRed[jlo][b] = accE;
    if (b < Asz) cRed[jlo][b] = accC;
  }
  __syncthreads();
  if (t < Bsz) {
    float e = 0.f;
    #pragma unroll
    for (int k = 0; k < 8; ++k) e += eRed[k][t];
    ws[OFF_E + (q * Lsz + i) * Bsz + t] = e;
  } else if (t < Bsz + Asz) {
    const int jj = t - Bsz;
    float c = 0.f;
    #pragma unroll
    for (int k = 0; k < 8; ++k) c += cRed[k][jj];
    ws[OFF_C + (q * Lsz + i) * Asz + jj] = c;
  }

  for (int sft = 32; sft >= 1; sft >>= 1) {
    rsq += __shfl_down(rsq, sft);
    rab += __shfl_down(rab, sft);
  }
  if ((t & 63) == 0) { wred[t >> 6] = rsq; wred[8 + (t >> 6)] = rab; }
  __syncthreads();
  if (t == 0) {
    float a = 0.f, bb2 = 0.f;
    for (int w = 0; w < BLK1 / 64; ++w) { a += wred[w]; bb2 += wred[8 + w]; }
    ws[OFF_RSQ + wg] = a;
    ws[OFF_RAB + wg] = bb2;
  }
}

// Kernel 2: one block per i (640 threads, t=j*32+b): assemble logits from the
// 4 quarter-partials, logsumexp per b, subtract energy, write per-(i,b).
#define BLK2 640
__global__ __launch_bounds__(BLK2) void k2(const int* __restrict__ x,
                                           const float* __restrict__ wsng,
                                           const float* __restrict__ ws,
                                           float* __restrict__ wso) {
  const int i = blockIdx.x;
  const int t = threadIdx.x;
  const int j = t >> 5, b = t & 31;
  __shared__ float l[Bsz * 21];

  float v = wsng[i * Asz + j];
  #pragma unroll
  for (int qq = 0; qq < NQ; ++qq) {
    v += ws[OFF_C + (qq * Lsz + i) * Asz + j];
    v += ws[OFF_G + ((size_t)(qq * Lsz + i) * Asz + j) * Bsz + b];
  }
  l[b * 21 + j] = v;
  __syncthreads();

  if (t < Bsz) {
    float m = -1e30f;
    #pragma unroll
    for (int jj = 0; jj < Asz; ++jj) m = fmaxf(m, l[t * 21 + jj]);
    float se = 0.f;
    #pragma unroll
    for (int jj = 0; jj < Asz; ++jj) se += __expf(l[t * 21 + jj] - m);
    float lse = m + __logf(se);
    float en = wsng[i * Asz + x[t * Lsz + i]];
    #pragma unroll
    for (int qq = 0; qq < NQ; ++qq) en += ws[OFF_E + (qq * Lsz + i) * Bsz + t];
    wso[OFF_K2 + i * Bsz + t] = lse - en;
  }
}

// Kernel 3: final scalar.
__global__ __launch_bounds__(256) void k3(const float* __restrict__ wsng,
                                          const float* __restrict__ ws,
                                          float* __restrict__ out) {
  const int t = threadIdx.x;
  float ssq = 0.f, sab = 0.f;
  for (int k = t; k < Lsz * Asz; k += 256) {
    float v = wsng[k];
    ssq += v * v; sab += fabsf(v);
  }
  float psq = 0.f, pab = 0.f;
  for (int k = t; k < NWG1; k += 256) {
    psq += ws[OFF_RSQ + k];
    pab += ws[OFF_RAB + k];
  }
  float fe = 0.f;
  for (int k = t; k < Lsz * Bsz; k += 256) fe += ws[OFF_K2 + k];

  const float LP = 51.0f;  // 0.2 * (L-1)
  float val = fe * (1.0f / Bsz) + (ssq + sab) + LP * (psq + pab);

  __shared__ float red[256];
  red[t] = val;
  __syncthreads();
  for (int s = 128; s >= 1; s >>= 1) {
    if (t < s) red[t] += red[t + s];
    __syncthreads();
  }
  if (t == 0) out[0] = red[0];
}

extern "C" void kernel_launch(void* const* d_in, const int* in_sizes, int n_in,
                              void* d_out, int out_size, void* d_ws, size_t ws_size,
                              hipStream_t stream) {
  const int*   x       = (const int*)d_in[0];
  const float* wsingle = (const float*)d_in[1];
  const float* wpair   = (const float*)d_in[2];
  float* ws  = (float*)d_ws;
  float* out = (float*)d_out;

  k1<<<NWG1, BLK1, 0, stream>>>(x, wpair, ws);
  k2<<<Lsz, BLK2, 0, stream>>>(x, wsingle, ws, ws);
  k3<<<1, 256, 0, stream>>>(wsingle, ws, out);
}

// Round 4
// 177.419 us; speedup vs baseline: 1.0473x; 1.0374x over previous
//
#include <hip/hip_runtime.h>
#include <cmath>

// Problem constants
#define Bsz 32
#define Lsz 256
#define Asz 20
#define NCHUNK 8        // p-chunks per i (32 p each)
#define PCH 32          // L / NCHUNK
#define GRP 16          // blocks staged per LDS group (16*400 = 6400 floats)
#define NGRP 2          // groups per chunk
#define BLK1 640        // t = j*32 + b  (j=t>>5 in 0..19, b=t&31)

// Workspace offsets (floats). Total ~1.43M floats = 5.7 MB.
#define OFF_G 0                                    // [c][i][b][j] p>i gather partials
#define OFF_C (NCHUNK*Lsz*Bsz*Asz)                 // [c][i][j]    b-independent (p<=i)
#define OFF_E (OFF_C + NCHUNK*Lsz*Asz)             // [c][i][b]    energy pair partials
#define OFF_RSQ (OFF_E + NCHUNK*Lsz*Bsz)           // [2048] per-wg sum w^2
#define OFF_RAB (OFF_RSQ + NCHUNK*Lsz)             // [2048] per-wg sum |w|
#define OFF_K2  (OFF_RAB + NCHUNK*Lsz)             // [L*B]  per-(i,b) lse-energy
#define OFF_TICKET (OFF_K2 + Lsz*Bsz)              // [1]    k2 arrival counter (int)

// Kernel 1: stream all of w_pair once. wg = (i, chunk c), grid 2048.
// Raw (unpadded) LDS block layout; lane map t=j*32+b makes the gather
// conflict-free (<=40 consecutive words per wave -> 2-way max, free).
__global__ __launch_bounds__(BLK1, 8) void k1(const int* __restrict__ x,
                                              const float* __restrict__ wp,
                                              float* __restrict__ ws) {
  const int wg = blockIdx.x;
  const int c = wg & (NCHUNK - 1);
  const int i = wg >> 3;
  const int t = threadIdx.x;
  const int j = t >> 5;         // 0..19
  const int b = t & 31;         // 0..31

  __shared__ float blk[GRP * 400];   // 25.6 KB
  __shared__ int   xs[PCH * Bsz];    // [dp][b] -> bank = b, conflict-free
  __shared__ int   xi[Bsz];
  __shared__ float wred[32];

  // zero the k2 arrival ticket (ws is re-poisoned before k1 each iteration;
  // k1->k2 kernel boundary publishes this store)
  if (wg == 0 && t == 0) *(int*)(ws + OFF_TICKET) = 0;

  const int pbase = c * PCH;
  for (int k = t; k < PCH * Bsz; k += BLK1) {
    int dp = k >> 5, bb = k & 31;
    xs[k] = x[bb * Lsz + pbase + dp];
  }
  if (t < Bsz) xi[t] = x[t * Lsz + i];

  float accJ = 0.f, accE = 0.f, accC = 0.f, rsq = 0.f, rab = 0.f;

  // chunk = 12800 floats = 3200 float4; group = 1600 float4
  const float4* wrow = (const float4*)(wp + (size_t)(i * Lsz + pbase) * 400);
  float4 v0 = wrow[t];
  float4 v1 = wrow[t + 640];
  float4 v2 = (t < 320) ? wrow[t + 1280] : make_float4(0.f, 0.f, 0.f, 0.f);

  for (int g = 0; g < NGRP; ++g) {
    // stage current group: contiguous b128 writes, no index math
    float4* bf4 = (float4*)blk;
    bf4[t] = v0;
    bf4[t + 640] = v1;
    if (t < 320) bf4[t + 1280] = v2;
    rsq += v0.x*v0.x + v0.y*v0.y + v0.z*v0.z + v0.w*v0.w;
    rsq += v1.x*v1.x + v1.y*v1.y + v1.z*v1.z + v1.w*v1.w;
    rab += fabsf(v0.x)+fabsf(v0.y)+fabsf(v0.z)+fabsf(v0.w);
    rab += fabsf(v1.x)+fabsf(v1.y)+fabsf(v1.z)+fabsf(v1.w);
    if (t < 320) {
      rsq += v2.x*v2.x + v2.y*v2.y + v2.z*v2.z + v2.w*v2.w;
      rab += fabsf(v2.x)+fabsf(v2.y)+fabsf(v2.z)+fabsf(v2.w);
    }
    __syncthreads();

    // prefetch next group (register path overlaps barrier+gather)
    if (g == 0) {
      v0 = wrow[1600 + t];
      v1 = wrow[1600 + t + 640];
      if (t < 320) v2 = wrow[1600 + t + 1280];
    }

    const int p0 = pbase + g * GRP;   // global p of LDS block 0
    // --- accJ: p > i, all waves, uniform trip count ---
    int ppstart = i + 1 - p0;
    if (ppstart < 0) ppstart = 0;
    const int jbase = j * Asz;
    for (int pp = ppstart; pp < GRP; ++pp) {
      int xv = xs[((g * GRP + pp) << 5) | b];
      accJ += blk[pp * 400 + jbase + xv];
    }
    // --- accE (lanes 0..31 of wave 0): all p ---
    if (t < Bsz) {
      const int ebase = xi[t] * Asz;
      for (int pp = 0; pp < GRP; ++pp) {
        int xv = xs[((g * GRP + pp) << 5) | t];
        accE += blk[pp * 400 + ebase + xv];
      }
    } else if (t < Bsz + Asz) {
      // --- accC (lanes 32..51 of wave 0): p<i -> col 19; p==i -> diag ---
      const int jj = t - Bsz;
      int pend = i - p0;
      if (pend > GRP) pend = GRP;
      for (int pp = 0; pp < pend; ++pp) accC += blk[pp * 400 + jj * Asz + 19];
      const int pd = i - p0;
      if (pd >= 0 && pd < GRP) accC += blk[pd * 400 + jj * Asz + jj];
    }
    __syncthreads();
  }

  ws[OFF_G + ((size_t)(c * Lsz + i) * Bsz + b) * Asz + j] = accJ;
  if (t < Bsz) ws[OFF_E + (c * Lsz + i) * Bsz + t] = accE;
  else if (t < Bsz + Asz) ws[OFF_C + (c * Lsz + i) * Asz + (t - Bsz)] = accC;

  // reg-stat reduction: wave shuffle then tiny LDS pass
  for (int s = 32; s >= 1; s >>= 1) {
    rsq += __shfl_down(rsq, s);
    rab += __shfl_down(rab, s);
  }
  if ((t & 63) == 0) { wred[t >> 6] = rsq; wred[16 + (t >> 6)] = rab; }
  __syncthreads();
  if (t == 0) {
    float a = 0.f, bb = 0.f;
    for (int w = 0; w < 10; ++w) { a += wred[w]; bb += wred[16 + w]; }
    ws[OFF_RSQ + wg] = a;
    ws[OFF_RAB + wg] = bb;
  }
}

// Kernel 2: one block per i (640 threads, t=j*32+b): assemble logits,
// logsumexp per (b), subtract energy, write per-(i,b) partial.
// The LAST block to finish (device-scope ticket) also performs the final
// scalar reduction (former k3), saving one kernel launch.
__global__ __launch_bounds__(BLK1) void k2(const int* __restrict__ x,
                                           const float* __restrict__ wsng,
                                           float* __restrict__ ws,
                                           float* __restrict__ out) {
  const int i = blockIdx.x;
  const int t = threadIdx.x;
  const int j = t >> 5, b = t & 31;
  __shared__ float l[Bsz * 21];
  __shared__ float sred[16];
  __shared__ int lastFlag;

  float v = wsng[i * Asz + j];
  #pragma unroll
  for (int c = 0; c < NCHUNK; ++c) {
    v += ws[OFF_C + (c * Lsz + i) * Asz + j];
    v += ws[OFF_G + ((size_t)(c * Lsz + i) * Bsz + b) * Asz + j];
  }
  l[b * 21 + j] = v;
  __syncthreads();

  if (t < Bsz) {
    float m = -1e30f;
    #pragma unroll
    for (int jj = 0; jj < Asz; ++jj) m = fmaxf(m, l[t * 21 + jj]);
    float se = 0.f;
    #pragma unroll
    for (int jj = 0; jj < Asz; ++jj) se += __expf(l[t * 21 + jj] - m);
    float lse = m + __logf(se);
    float en = wsng[i * Asz + x[t * Lsz + i]];
    #pragma unroll
    for (int c = 0; c < NCHUNK; ++c) en += ws[OFF_E + (c * Lsz + i) * Bsz + t];
    ws[OFF_K2 + i * Bsz + t] = lse - en;
  }

  // ---- arrival ticket: last block does the final reduction ----
  __syncthreads();   // K2 row fully written by lanes t<32
  if (t == 0) {
    __threadfence(); // publish this block's K2 row (device scope)
    int old = __hip_atomic_fetch_add((int*)(ws + OFF_TICKET), 1,
                                     __ATOMIC_ACQ_REL, __HIP_MEMORY_SCOPE_AGENT);
    lastFlag = (old == Lsz - 1);
  }
  __syncthreads();
  if (!lastFlag) return;
  __threadfence();   // acquire: make all blocks' K2 rows visible

  // ---- former k3 body, strided over 640 threads ----
  float ssq = 0.f, sab = 0.f;
  for (int k = t; k < Lsz * Asz; k += BLK1) {
    float w = wsng[k];
    ssq += w * w; sab += fabsf(w);
  }
  float psq = 0.f, pab = 0.f;
  for (int k = t; k < NCHUNK * Lsz; k += BLK1) {
    psq += ws[OFF_RSQ + k];
    pab += ws[OFF_RAB + k];
  }
  float fe = 0.f;
  for (int k = t; k < Lsz * Bsz; k += BLK1) fe += ws[OFF_K2 + k];

  const float LP = 51.0f;  // 0.2 * (L-1)
  float val = fe * (1.0f / Bsz) + (ssq + sab) + LP * (psq + pab);

  for (int s = 32; s >= 1; s >>= 1) val += __shfl_down(val, s);
  if ((t & 63) == 0) sred[t >> 6] = val;
  __syncthreads();
  if (t == 0) {
    float a = 0.f;
    for (int w = 0; w < BLK1 / 64; ++w) a += sred[w];
    out[0] = a;
  }
}

extern "C" void kernel_launch(void* const* d_in, const int* in_sizes, int n_in,
                              void* d_out, int out_size, void* d_ws, size_t ws_size,
                              hipStream_t stream) {
  const int*   x       = (const int*)d_in[0];
  const float* wsingle = (const float*)d_in[1];
  const float* wpair   = (const float*)d_in[2];
  float* ws  = (float*)d_ws;
  float* out = (float*)d_out;

  k1<<<Lsz * NCHUNK, BLK1, 0, stream>>>(x, wpair, ws);
  k2<<<Lsz, BLK1, 0, stream>>>(x, wsingle, ws, out);
}